// Round 6
// baseline (328.592 us; speedup 1.0000x reference)
//
#include <hip/hip_runtime.h>
#include <math.h>

#define L_SEQ 8192
#define B_SZ  2
#define CH    256
#define NLEV  4

typedef __attribute__((ext_vector_type(8))) short bf16x8;
typedef __attribute__((ext_vector_type(4))) float f32x4;

static __device__ __forceinline__ float sigmoidf_(float x) {
    return 1.0f / (1.0f + expf(-x));
}

// bf16 (stored as ushort) <-> fp32 helpers. bf2f is exact; f2b is RNE.
static __device__ __forceinline__ float bf2f_(unsigned short u) {
    union { unsigned int ui; float f; } x;
    x.ui = ((unsigned int)u) << 16;
    return x.f;
}
static __device__ __forceinline__ unsigned short f2b_(float f) {
    union { float f; unsigned int u; } x;
    x.f = f;
    unsigned int lsb = (x.u >> 16) & 1u;
    unsigned int r = x.u + 0x7fffu + lsb;
    return (unsigned short)(r >> 16);
}
static __device__ __forceinline__ float4 ldb4_(const unsigned short* p) {
    ushort4 u = *(const ushort4*)p;
    return make_float4(bf2f_(u.x), bf2f_(u.y), bf2f_(u.z), bf2f_(u.w));
}

// ---------------------------------------------------------------------------
// Fused fp32->bf16 prep: guard row (zeros) + x16 + qkv_w + out_w + stem_w.
// ---------------------------------------------------------------------------
__global__ void prep_kernel(const float* __restrict__ x,
                            const float* __restrict__ qkv_w,
                            const float* __restrict__ out_w,
                            const float* __restrict__ stem_w,
                            unsigned short* __restrict__ x16g,
                            unsigned short* __restrict__ qw16,
                            unsigned short* __restrict__ ow16,
                            unsigned short* __restrict__ sw16)
{
    int i = blockIdx.x * 256 + threadIdx.x;
    if (i < 256) { x16g[i] = 0; return; }           // guard row of zeros
    i -= 256;
    if (i < 4194304) { x16g[256 + i] = f2b_(x[i]); return; }
    i -= 4194304;
    if (i < 196608) { qw16[i] = f2b_(qkv_w[i]); return; }
    i -= 196608;
    if (i < 65536) { ow16[i] = f2b_(out_w[i]); return; }
    i -= 65536;
    {   // stem W: (256,512); k<256 -> tap0, else tap1
        int k = i & 511, n = i >> 9;
        float v = (k < 256) ? stem_w[(size_t)n * 512 + k * 2]
                            : stem_w[(size_t)n * 512 + (k - 256) * 2 + 1];
        sw16[i] = f2b_(v);
    }
}

// ---------------------------------------------------------------------------
// Stem conv as MFMA GEMM, staging A directly from x16 (guard row at offset 0,
// row m data at x16g + (m+1)*256). Writes h16 (bias added).
// ---------------------------------------------------------------------------
__global__ __launch_bounds__(256) void stem_gemm_bf16(
    const unsigned short* __restrict__ x16g, const unsigned short* __restrict__ W,
    unsigned short* __restrict__ outB, const float* __restrict__ bias)
{
    __shared__ unsigned short As[128 * 32];
    __shared__ unsigned short Bs[128 * 32];
    const int tid  = threadIdx.x;
    const int wave = tid >> 6;
    const int lane = tid & 63;
    const int bm = blockIdx.y * 128;
    const int bn = blockIdx.x * 128;
    const int wm = (wave & 1) * 64;
    const int wn = (wave >> 1) * 64;
    const int srow = lane >> 2;
    const int scol = (lane & 3) * 8;

    f32x4 acc[4][4] = {};

    for (int k0 = 0; k0 < 512; k0 += 32) {
        __syncthreads();
        #pragma unroll
        for (int c = 0; c < 2; ++c) {
            const int chunk = c * 4 + wave;
            const int row = bm + chunk * 16 + srow;
            const int t = row & (L_SEQ - 1);
            const unsigned short* ga;
            if (k0 < 256)
                ga = x16g + (t > 0 ? (size_t)row * 256 : 0) + k0 + scol;
            else
                ga = x16g + ((size_t)row + 1) * 256 + (k0 - 256) + scol;
            const unsigned short* gw = W + (size_t)(bn + chunk * 16 + srow) * 512 + k0 + scol;
            __builtin_amdgcn_global_load_lds(
                (const __attribute__((address_space(1))) void*)ga,
                (__attribute__((address_space(3))) void*)(As + chunk * 16 * 32),
                16, 0, 0);
            __builtin_amdgcn_global_load_lds(
                (const __attribute__((address_space(1))) void*)gw,
                (__attribute__((address_space(3))) void*)(Bs + chunk * 16 * 32),
                16, 0, 0);
        }
        __syncthreads();

        bf16x8 af[4], bf[4];
        const int fr = lane & 15;
        const int kk = (lane >> 4) * 8;
        #pragma unroll
        for (int i = 0; i < 4; ++i) {
            af[i] = *(const bf16x8*)(As + (wm + i * 16 + fr) * 32 + kk);
            bf[i] = *(const bf16x8*)(Bs + (wn + i * 16 + fr) * 32 + kk);
        }
        #pragma unroll
        for (int i = 0; i < 4; ++i)
            #pragma unroll
            for (int j = 0; j < 4; ++j)
                acc[i][j] = __builtin_amdgcn_mfma_f32_16x16x32_bf16(
                    af[i], bf[j], acc[i][j], 0, 0, 0);
    }

    const int cn = lane & 15;
    const int cr = (lane >> 4) * 4;
    #pragma unroll
    for (int i = 0; i < 4; ++i)
        #pragma unroll
        for (int r = 0; r < 4; ++r) {
            const int m = bm + wm + i * 16 + cr + r;
            #pragma unroll
            for (int j = 0; j < 4; ++j) {
                const int n = bn + wn + j * 16 + cn;
                outB[(size_t)m * CH + n] = f2b_(acc[i][j][r] + bias[n]);
            }
        }
}

// ---------------------------------------------------------------------------
// Generic MFMA bf16 GEMM (m97 structure): out = A @ W^T, bf16 out.
// ---------------------------------------------------------------------------
__global__ __launch_bounds__(256) void gemm_bf16(
    const unsigned short* __restrict__ A, const unsigned short* __restrict__ W,
    unsigned short* __restrict__ outB, int M, int N, int Kd)
{
    __shared__ unsigned short As[128 * 32];
    __shared__ unsigned short Bs[128 * 32];
    const int tid  = threadIdx.x;
    const int wave = tid >> 6;
    const int lane = tid & 63;
    const int bm = blockIdx.y * 128;
    const int bn = blockIdx.x * 128;
    const int wm = (wave & 1) * 64;
    const int wn = (wave >> 1) * 64;
    const int srow = lane >> 2;
    const int scol = (lane & 3) * 8;

    f32x4 acc[4][4] = {};

    for (int k0 = 0; k0 < Kd; k0 += 32) {
        __syncthreads();
        #pragma unroll
        for (int c = 0; c < 2; ++c) {
            const int chunk = c * 4 + wave;
            const int row = chunk * 16 + srow;
            const unsigned short* ga = A + (size_t)(bm + row) * Kd + k0 + scol;
            const unsigned short* gw = W + (size_t)(bn + row) * Kd + k0 + scol;
            __builtin_amdgcn_global_load_lds(
                (const __attribute__((address_space(1))) void*)ga,
                (__attribute__((address_space(3))) void*)(As + chunk * 16 * 32),
                16, 0, 0);
            __builtin_amdgcn_global_load_lds(
                (const __attribute__((address_space(1))) void*)gw,
                (__attribute__((address_space(3))) void*)(Bs + chunk * 16 * 32),
                16, 0, 0);
        }
        __syncthreads();

        bf16x8 af[4], bf[4];
        const int fr = lane & 15;
        const int kk = (lane >> 4) * 8;
        #pragma unroll
        for (int i = 0; i < 4; ++i) {
            af[i] = *(const bf16x8*)(As + (wm + i * 16 + fr) * 32 + kk);
            bf[i] = *(const bf16x8*)(Bs + (wn + i * 16 + fr) * 32 + kk);
        }
        #pragma unroll
        for (int i = 0; i < 4; ++i)
            #pragma unroll
            for (int j = 0; j < 4; ++j)
                acc[i][j] = __builtin_amdgcn_mfma_f32_16x16x32_bf16(
                    af[i], bf[j], acc[i][j], 0, 0, 0);
    }

    const int cn = lane & 15;
    const int cr = (lane >> 4) * 4;
    #pragma unroll
    for (int i = 0; i < 4; ++i)
        #pragma unroll
        for (int r = 0; r < 4; ++r) {
            const int m = bm + wm + i * 16 + cr + r;
            const size_t rowoff = (size_t)m * N;
            #pragma unroll
            for (int j = 0; j < 4; ++j)
                outB[rowoff + bn + wn + j * 16 + cn] = f2b_(acc[i][j][r]);
        }
}

// ---------------------------------------------------------------------------
// Fused local attention + width head + out-proj + downsample.
// Block = 64 positions (4 waves x 16 rows).
//   phase 1: K halo [80][272] in LDS; fused width dot; S = Q*K^T (MFMA);
//            masked softmax; P (+1 center for o+v residual) -> pb.
//   phase 2: Vt [256][84] (same LDS region); PV MFMA -> ovS [64][260] (LDS).
//   phase 3: out = ovS @ ow^T (B-frags streamed from L2-hot ow16);
//            epilogue: bf16 level output + pair-mean downsample.
// LDS total = 80,896 B -> 2 blocks/CU.
// ---------------------------------------------------------------------------
__global__ __launch_bounds__(256) void attn_out_mfma_kernel(
    const unsigned short* __restrict__ qkv, const unsigned short* __restrict__ h16,
    const float* __restrict__ ww, const float* __restrict__ wbp,
    const unsigned short* __restrict__ ow,
    unsigned short* __restrict__ l16out, unsigned short* __restrict__ dsB, int l)
{
    __shared__ unsigned short kv[21760];   // K [80][272] then Vt [256][84]
    __shared__ unsigned short pb[2048];    // P per wave [16][32]
    __shared__ unsigned short ovS[16640];  // (o+v) [64][260]

    const int tid  = threadIdx.x;
    const int wave = tid >> 6;
    const int lane = tid & 63;
    const int q    = lane >> 4;
    const int n    = lane & 15;

    const int blocks_per_seq = l >> 6;
    const int b  = blockIdx.x / blocks_per_seq;
    const int t0 = (blockIdx.x % blocks_per_seq) << 6;
    const size_t seqbase = (size_t)b * l;
    const int row0 = t0 + wave * 16;

    // ---- phase 1: stage K halo ----
    #pragma unroll
    for (int i = 0; i < 10; ++i) {
        int task = i * 256 + tid;
        int r = task >> 5, chunk = task & 31;
        int grow = t0 - 8 + r;
        bf16x8 val = {0, 0, 0, 0, 0, 0, 0, 0};
        if (grow >= 0 && grow < l)
            val = *(const bf16x8*)(qkv + (seqbase + grow) * 768 + 256 + chunk * 8);
        *(bf16x8*)(kv + r * 272 + chunk * 8) = val;
    }

    // ---- fused width: lane (q,n) accumulates cols [q*64, q*64+64) of row n ----
    float wdot = 0.0f;
    {
        const unsigned short* hrow = h16 + (seqbase + row0 + n) * 256 + q * 64;
        #pragma unroll
        for (int jj = 0; jj < 8; ++jj) {
            bf16x8 hv = *(const bf16x8*)(hrow + jj * 8);
            float4 wa = *((const float4*)(ww + q * 64 + jj * 8));
            float4 wc = *((const float4*)(ww + q * 64 + jj * 8 + 4));
            wdot += bf2f_(((unsigned short*)&hv)[0]) * wa.x
                  + bf2f_(((unsigned short*)&hv)[1]) * wa.y
                  + bf2f_(((unsigned short*)&hv)[2]) * wa.z
                  + bf2f_(((unsigned short*)&hv)[3]) * wa.w
                  + bf2f_(((unsigned short*)&hv)[4]) * wc.x
                  + bf2f_(((unsigned short*)&hv)[5]) * wc.y
                  + bf2f_(((unsigned short*)&hv)[6]) * wc.z
                  + bf2f_(((unsigned short*)&hv)[7]) * wc.w;
        }
    }
    wdot += __shfl_xor(wdot, 16, 64);
    wdot += __shfl_xor(wdot, 32, 64);
    const float w_n = sigmoidf_(wdot + wbp[0]) * 8.0f + 0.5f;  // width of row n

    __syncthreads();

    // Q A-fragments straight from global
    bf16x8 qf[8];
    const unsigned short* qrow = qkv + (seqbase + row0 + n) * 768;
    #pragma unroll
    for (int kk = 0; kk < 8; ++kk)
        qf[kk] = *(const bf16x8*)(qrow + kk * 32 + q * 8);

    f32x4 accS[2] = {};
    #pragma unroll
    for (int kk = 0; kk < 8; ++kk) {
        #pragma unroll
        for (int h = 0; h < 2; ++h) {
            bf16x8 bk = *(const bf16x8*)(kv + (wave * 16 + h * 16 + n) * 272 +
                                         kk * 32 + q * 8);
            accS[h] = __builtin_amdgcn_mfma_f32_16x16x32_bf16(
                qf[kk], bk, accS[h], 0, 0, 0);
        }
    }

    // widths for this lane's 4 C-layout rows (i = q*4+r), pulled via shfl
    float wd[4];
    #pragma unroll
    for (int r = 0; r < 4; ++r) wd[r] = __shfl(w_n, q * 4 + r, 64);

    // mask + scale (C-layout: col c = h*16+n, row i = q*4+r)
    float s[2][4];
    #pragma unroll
    for (int h = 0; h < 2; ++h)
        #pragma unroll
        for (int r = 0; r < 4; ++r) {
            int ii = q * 4 + r;
            int c  = h * 16 + n;
            int w  = c - ii;
            float dist = fabsf((float)w - 8.0f);
            float sm = sigmoidf_((wd[r] - dist) * 5.0f);
            float v = accS[h][r] * 0.0625f - (1.0f - sm) * 10000.0f;
            s[h][r] = (w >= 0 && w <= 16) ? v : -3.0e38f;
        }

    // softmax over the row (16 lanes of the quad hold the 32 cols)
    float mx[4], sum[4];
    #pragma unroll
    for (int r = 0; r < 4; ++r) mx[r] = fmaxf(s[0][r], s[1][r]);
    #pragma unroll
    for (int m = 1; m < 16; m <<= 1)
        #pragma unroll
        for (int r = 0; r < 4; ++r) mx[r] = fmaxf(mx[r], __shfl_xor(mx[r], m, 64));
    float e[2][4];
    #pragma unroll
    for (int h = 0; h < 2; ++h)
        #pragma unroll
        for (int r = 0; r < 4; ++r) e[h][r] = expf(s[h][r] - mx[r]);
    #pragma unroll
    for (int r = 0; r < 4; ++r) sum[r] = e[0][r] + e[1][r];
    #pragma unroll
    for (int m = 1; m < 16; m <<= 1)
        #pragma unroll
        for (int r = 0; r < 4; ++r) sum[r] += __shfl_xor(sum[r], m, 64);

    // write P (bf16), folding the o+v residual: +1 at center col c == ii+8
    #pragma unroll
    for (int h = 0; h < 2; ++h)
        #pragma unroll
        for (int r = 0; r < 4; ++r) {
            int ii = q * 4 + r, c = h * 16 + n;
            float p = e[h][r] / sum[r];
            if (c == ii + 8) p += 1.0f;
            pb[wave * 512 + ii * 32 + c] = f2b_(p);
        }
    __syncthreads();  // all waves done reading K region

    // ---- phase 2: stage V transposed into kv as Vt[256][84] ----
    #pragma unroll
    for (int p5 = 0; p5 < 5; ++p5)
        #pragma unroll
        for (int cc = 0; cc < 2; ++cc) {
            int r = p5 * 16 + (tid & 15);
            int chunk = cc * 16 + (tid >> 4);
            int grow = t0 - 8 + r;
            bf16x8 val = {0, 0, 0, 0, 0, 0, 0, 0};
            if (grow >= 0 && grow < l)
                val = *(const bf16x8*)(qkv + (seqbase + grow) * 768 + 512 + chunk * 8);
            #pragma unroll
            for (int jj = 0; jj < 8; ++jj)
                kv[(chunk * 8 + jj) * 84 + r] = ((unsigned short*)&val)[jj];
        }
    __syncthreads();

    // ---- PV: A = P (A-layout), B = Vt slices -> ovS (wave-private rows) ----
    bf16x8 pf = *(const bf16x8*)(pb + wave * 512 + n * 32 + q * 8);
    #pragma unroll
    for (int chunk = 0; chunk < 16; ++chunk) {
        bf16x8 vf = *(const bf16x8*)(kv + (chunk * 16 + n) * 84 + wave * 16 + q * 8);
        f32x4 z = {};
        f32x4 o = __builtin_amdgcn_mfma_f32_16x16x32_bf16(pf, vf, z, 0, 0, 0);
        #pragma unroll
        for (int r = 0; r < 4; ++r)
            ovS[(wave * 16 + q * 4 + r) * 260 + chunk * 16 + n] = f2b_(o[r]);
    }
    // no barrier: each wave reads only its own 16 ovS rows below

    // ---- phase 3: out-proj 16x256 = ovS(16x256) @ ow^T ----
    bf16x8 af2[8];
    #pragma unroll
    for (int kk = 0; kk < 8; ++kk)
        af2[kk] = *(const bf16x8*)(ovS + (wave * 16 + n) * 260 + kk * 32 + q * 8);

    const int base = row0 + q * 4;  // even; lane's 4 consecutive output rows
    #pragma unroll 2
    for (int ct = 0; ct < 16; ++ct) {
        f32x4 acc = {};
        #pragma unroll
        for (int kk = 0; kk < 8; ++kk) {
            bf16x8 bw = *(const bf16x8*)(ow + (size_t)(ct * 16 + n) * 256 +
                                         kk * 32 + q * 8);
            acc = __builtin_amdgcn_mfma_f32_16x16x32_bf16(af2[kk], bw, acc, 0, 0, 0);
        }
        const int col = ct * 16 + n;
        float v0 = acc[0], v1 = acc[1], v2 = acc[2], v3 = acc[3];
        l16out[(seqbase + base + 0) * CH + col] = f2b_(v0);
        l16out[(seqbase + base + 1) * CH + col] = f2b_(v1);
        l16out[(seqbase + base + 2) * CH + col] = f2b_(v2);
        l16out[(seqbase + base + 3) * CH + col] = f2b_(v3);
        if (dsB) {
            const size_t dsrow = (seqbase + base) >> 1;
            dsB[dsrow * CH + col]       = f2b_(0.5f * (v0 + v1));
            dsB[(dsrow + 1) * CH + col] = f2b_(0.5f * (v2 + v3));
        }
    }
}

// ---------------------------------------------------------------------------
// s[b,t] = sum_lev lev16[lev][b, t>>lev, :]·query[lev*256:+256] (wave/(b,t))
// ---------------------------------------------------------------------------
__global__ __launch_bounds__(256) void gattn_score_kernel(
    const unsigned short* __restrict__ l0, const unsigned short* __restrict__ l1,
    const unsigned short* __restrict__ l2, const unsigned short* __restrict__ l3,
    const float* __restrict__ query, float* __restrict__ s)
{
    const int lane = threadIdx.x & 63;
    const int row = blockIdx.x * 4 + (threadIdx.x >> 6);
    const int b = row >> 13;
    const int t = row & (L_SEQ - 1);
    const unsigned short* levp[4] = {l0, l1, l2, l3};
    float part = 0.0f;
    #pragma unroll
    for (int lev = 0; lev < 4; ++lev) {
        const unsigned short* lp = levp[lev] +
            ((size_t)b * (L_SEQ >> lev) + (t >> lev)) * CH + lane * 4;
        float4 hv = ldb4_(lp);
        float4 qv = *((const float4*)(query + lev * CH) + lane);
        part += hv.x * qv.x + hv.y * qv.y + hv.z * qv.z + hv.w * qv.w;
    }
    #pragma unroll
    for (int m = 1; m < 64; m <<= 1) part += __shfl_xor(part, m, 64);
    if (lane == 0) s[row] = part;
}

// Softmax over L per batch. grid = B, block = 1024.
__global__ __launch_bounds__(1024) void softmax_L_kernel(
    const float* __restrict__ s, float* __restrict__ p)
{
    __shared__ float red[1024];
    const int b = blockIdx.x, tid = threadIdx.x;
    const float* sb = s + (size_t)b * L_SEQ;
    float mx = -1e30f;
    for (int i = tid; i < L_SEQ; i += 1024) mx = fmaxf(mx, sb[i]);
    red[tid] = mx; __syncthreads();
    for (int o = 512; o > 0; o >>= 1) {
        if (tid < o) red[tid] = fmaxf(red[tid], red[tid + o]);
        __syncthreads();
    }
    mx = red[0]; __syncthreads();
    float sum = 0.0f;
    for (int i = tid; i < L_SEQ; i += 1024) sum += expf(sb[i] - mx);
    red[tid] = sum; __syncthreads();
    for (int o = 512; o > 0; o >>= 1) {
        if (tid < o) red[tid] += red[tid + o];
        __syncthreads();
    }
    const float inv = 1.0f / red[0];
    for (int i = tid; i < L_SEQ; i += 1024) p[(size_t)b * L_SEQ + i] = expf(sb[i] - mx) * inv;
}

// Partial global-context over bf16 levels: grid (64 chunks, B), block 1024.
__global__ __launch_bounds__(1024) void ctx_partial_kernel(
    const float* __restrict__ p,
    const unsigned short* __restrict__ l0, const unsigned short* __restrict__ l1,
    const unsigned short* __restrict__ l2, const unsigned short* __restrict__ l3,
    float* __restrict__ partials)
{
    const int d = threadIdx.x;
    const int lev = d >> 8, c = d & 255;
    const int chunk = blockIdx.x, b = blockIdx.y;
    const unsigned short* lp = (lev == 0) ? l0 : (lev == 1) ? l1 : (lev == 2) ? l2 : l3;
    lp += (size_t)b * (L_SEQ >> lev) * CH;
    const float* pbv = p + (size_t)b * L_SEQ;
    float acc = 0.0f;
    const int t0 = chunk * 128;
    #pragma unroll 4
    for (int t = t0; t < t0 + 128; ++t)
        acc += pbv[t] * bf2f_(lp[(size_t)(t >> lev) * CH + c]);
    partials[(size_t)(b * 64 + chunk) * 1024 + d] = acc;
}

// grid (4, B), block 256: ctx[b*1024+d] = sum over 64 chunks
__global__ __launch_bounds__(256) void ctx_reduce_kernel(
    const float* __restrict__ partials, float* __restrict__ ctx)
{
    const int b = blockIdx.y;
    const int d = blockIdx.x * 256 + threadIdx.x;
    float acc = 0.0f;
    #pragma unroll
    for (int c = 0; c < 64; ++c) acc += partials[(size_t)(b * 64 + c) * 1024 + d];
    ctx[b * 1024 + d] = acc;
}

// film[b,j] = ctx[b,:]·fw[j,:] + fb[j]. One wave per j, both batches.
__global__ __launch_bounds__(256) void film_kernel(
    const float* __restrict__ ctx, const float* __restrict__ fw,
    const float* __restrict__ fb, float* __restrict__ film)
{
    const int lane = threadIdx.x & 63;
    const int j = blockIdx.x * 4 + (threadIdx.x >> 6);  // 0..511
    float acc0 = 0.0f, acc1 = 0.0f;
    #pragma unroll
    for (int r = 0; r < 4; ++r) {
        float4 w4 = *((const float4*)(fw + (size_t)j * 1024 + r * 256) + lane);
        float4 c0 = *((const float4*)(ctx + r * 256) + lane);
        float4 c1 = *((const float4*)(ctx + 1024 + r * 256) + lane);
        acc0 += w4.x * c0.x + w4.y * c0.y + w4.z * c0.z + w4.w * c0.w;
        acc1 += w4.x * c1.x + w4.y * c1.y + w4.z * c1.z + w4.w * c1.w;
    }
    #pragma unroll
    for (int m = 1; m < 64; m <<= 1) {
        acc0 += __shfl_xor(acc0, m, 64);
        acc1 += __shfl_xor(acc1, m, 64);
    }
    if (lane == 0) {
        float b = fb[j];
        film[j] = acc0 + b;
        film[512 + j] = acc1 + b;
    }
}

// out = l16_0 * (1 + scale_f) + bias_f, 4 elem/thread (ushort4 -> float4)
__global__ void final_kernel(const unsigned short* __restrict__ lev0,
                             const float* __restrict__ film,
                             float* __restrict__ out)
{
    size_t n4 = ((size_t)blockIdx.x * 256 + threadIdx.x) * 4;
    int c = (int)(n4 & (CH - 1));
    int b = (int)(n4 >> 21);  // L*C = 2^21
    float4 h = ldb4_(lev0 + n4);
    const float* fs = film + b * 512;
    float4 o;
    o.x = h.x * (1.0f + fs[c + 0]) + fs[256 + c + 0];
    o.y = h.y * (1.0f + fs[c + 1]) + fs[256 + c + 1];
    o.z = h.z * (1.0f + fs[c + 2]) + fs[256 + c + 2];
    o.w = h.w * (1.0f + fs[c + 3]) + fs[256 + c + 3];
    *(float4*)(out + n4) = o;
}

extern "C" void kernel_launch(void* const* d_in, const int* in_sizes, int n_in,
                              void* d_out, int out_size, void* d_ws, size_t ws_size,
                              hipStream_t stream) {
    const float* x       = (const float*)d_in[0];
    const float* stem_w  = (const float*)d_in[1];
    const float* stem_b  = (const float*)d_in[2];
    const float* qkv_w   = (const float*)d_in[3];
    const float* width_w = (const float*)d_in[4];
    const float* width_b = (const float*)d_in[5];
    const float* out_w   = (const float*)d_in[6];
    const float* query   = (const float*)d_in[7];
    const float* film_w  = (const float*)d_in[8];
    const float* film_b  = (const float*)d_in[9];
    float* out = (float*)d_out;
    float* ws  = (float*)d_ws;

    // ---- workspace layout (fp32 region then bf16 region) ----
    float* sbuf     = ws;                       // 16,384
    float* pbuf     = sbuf + 16384;             // 16,384
    float* partials = pbuf + 16384;             // 131,072
    float* ctx      = partials + 131072;        // 2,048
    float* film     = ctx + 2048;               // 1,024
    unsigned short* x16g  = (unsigned short*)(film + 1024);  // 256 guard + 4,194,304
    unsigned short* h16_0 = x16g + 4194560;     // 4,194,304
    unsigned short* h16_1 = h16_0 + 4194304;    // 2,097,152
    unsigned short* h16_2 = h16_1 + 2097152;    // 1,048,576
    unsigned short* h16_3 = h16_2 + 1048576;    //   524,288
    unsigned short* qkv16 = h16_3 + 524288;     // 12,582,912
    unsigned short* l16_0 = qkv16 + 12582912;   // 4,194,304
    unsigned short* l16_1 = l16_0 + 4194304;    // 2,097,152
    unsigned short* l16_2 = l16_1 + 2097152;    // 1,048,576
    unsigned short* l16_3 = l16_2 + 1048576;    //   524,288
    unsigned short* qw16  = l16_3 + 524288;     //   196,608
    unsigned short* ow16  = qw16 + 196608;      //    65,536
    unsigned short* sw16  = ow16 + 65536;       //   131,072
    unsigned short* h16[4]  = {h16_0, h16_1, h16_2, h16_3};
    unsigned short* l16[4]  = {l16_0, l16_1, l16_2, l16_3};

    // ---- fused prep (guard + x16 + all weights) ----
    prep_kernel<<<(256 + 4194304 + 196608 + 65536 + 131072) / 256, 256, 0, stream>>>(
        x, qkv_w, out_w, stem_w, x16g, qw16, ow16, sw16);

    // ---- stem conv as bf16 GEMM (A staged directly from x16) ----
    stem_gemm_bf16<<<dim3(CH / 128, B_SZ * L_SEQ / 128), 256, 0, stream>>>(
        x16g, sw16, h16_0, stem_b);

    // ---- hierarchy levels: qkv GEMM + fused attn/out/downsample ----
    for (int i = 0; i < NLEV; ++i) {
        const int l = L_SEQ >> i;
        const int M = B_SZ * l;
        gemm_bf16<<<dim3(768 / 128, M / 128), 256, 0, stream>>>(
            h16[i], qw16, qkv16, M, 768, CH);
        attn_out_mfma_kernel<<<M / 64, 256, 0, stream>>>(
            qkv16, h16[i], width_w, width_b, ow16, l16[i],
            (i < NLEV - 1) ? h16[i + 1] : nullptr, l);
    }

    // ---- global attention + FiLM ----
    gattn_score_kernel<<<B_SZ * L_SEQ / 4, 256, 0, stream>>>(
        l16_0, l16_1, l16_2, l16_3, query, sbuf);
    softmax_L_kernel<<<B_SZ, 1024, 0, stream>>>(sbuf, pbuf);
    ctx_partial_kernel<<<dim3(64, B_SZ), 1024, 0, stream>>>(
        pbuf, l16_0, l16_1, l16_2, l16_3, partials);
    ctx_reduce_kernel<<<dim3(4, B_SZ), 256, 0, stream>>>(partials, ctx);
    film_kernel<<<128, 256, 0, stream>>>(ctx, film_w, film_b, film);
    final_kernel<<<(B_SZ * L_SEQ * CH) / 1024, 256, 0, stream>>>(l16_0, film, out);
}

// Round 7
// 267.088 us; speedup vs baseline: 1.2303x; 1.2303x over previous
//
#include <hip/hip_runtime.h>
#include <math.h>

#define L_SEQ 8192
#define B_SZ  2
#define CH    256
#define NLEV  4

typedef __attribute__((ext_vector_type(8))) short bf16x8;
typedef __attribute__((ext_vector_type(4))) float f32x4;

static __device__ __forceinline__ float sigmoidf_(float x) {
    return 1.0f / (1.0f + expf(-x));
}

// bf16 (stored as ushort) <-> fp32 helpers. bf2f is exact; f2b is RNE.
static __device__ __forceinline__ float bf2f_(unsigned short u) {
    union { unsigned int ui; float f; } x;
    x.ui = ((unsigned int)u) << 16;
    return x.f;
}
static __device__ __forceinline__ unsigned short f2b_(float f) {
    union { float f; unsigned int u; } x;
    x.f = f;
    unsigned int lsb = (x.u >> 16) & 1u;
    unsigned int r = x.u + 0x7fffu + lsb;
    return (unsigned short)(r >> 16);
}
static __device__ __forceinline__ float4 ldb4_(const unsigned short* p) {
    ushort4 u = *(const ushort4*)p;
    return make_float4(bf2f_(u.x), bf2f_(u.y), bf2f_(u.z), bf2f_(u.w));
}

// ---------------------------------------------------------------------------
// Fused fp32->bf16 prep: guard row (zeros) + x16 + qkv_w + out_w + stem_w.
// ---------------------------------------------------------------------------
__global__ void prep_kernel(const float* __restrict__ x,
                            const float* __restrict__ qkv_w,
                            const float* __restrict__ out_w,
                            const float* __restrict__ stem_w,
                            unsigned short* __restrict__ x16g,
                            unsigned short* __restrict__ qw16,
                            unsigned short* __restrict__ ow16,
                            unsigned short* __restrict__ sw16)
{
    int i = blockIdx.x * 256 + threadIdx.x;
    if (i < 256) { x16g[i] = 0; return; }           // guard row of zeros
    i -= 256;
    if (i < 4194304) { x16g[256 + i] = f2b_(x[i]); return; }
    i -= 4194304;
    if (i < 196608) { qw16[i] = f2b_(qkv_w[i]); return; }
    i -= 196608;
    if (i < 65536) { ow16[i] = f2b_(out_w[i]); return; }
    i -= 65536;
    {   // stem W: (256,512); k<256 -> tap0, else tap1
        int k = i & 511, n = i >> 9;
        float v = (k < 256) ? stem_w[(size_t)n * 512 + k * 2]
                            : stem_w[(size_t)n * 512 + (k - 256) * 2 + 1];
        sw16[i] = f2b_(v);
    }
}

// ---------------------------------------------------------------------------
// Stem conv as MFMA GEMM, staging A directly from x16 (guard row at offset 0,
// row m data at x16g + (m+1)*256). Writes h16 (bias added).
// ---------------------------------------------------------------------------
__global__ __launch_bounds__(256) void stem_gemm_bf16(
    const unsigned short* __restrict__ x16g, const unsigned short* __restrict__ W,
    unsigned short* __restrict__ outB, const float* __restrict__ bias)
{
    __shared__ unsigned short As[128 * 32];
    __shared__ unsigned short Bs[128 * 32];
    const int tid  = threadIdx.x;
    const int wave = tid >> 6;
    const int lane = tid & 63;
    const int bm = blockIdx.y * 128;
    const int bn = blockIdx.x * 128;
    const int wm = (wave & 1) * 64;
    const int wn = (wave >> 1) * 64;
    const int srow = lane >> 2;
    const int scol = (lane & 3) * 8;

    f32x4 acc[4][4] = {};

    for (int k0 = 0; k0 < 512; k0 += 32) {
        __syncthreads();
        #pragma unroll
        for (int c = 0; c < 2; ++c) {
            const int chunk = c * 4 + wave;
            const int row = bm + chunk * 16 + srow;
            const int t = row & (L_SEQ - 1);
            const unsigned short* ga;
            if (k0 < 256)
                ga = x16g + (t > 0 ? (size_t)row * 256 : 0) + k0 + scol;
            else
                ga = x16g + ((size_t)row + 1) * 256 + (k0 - 256) + scol;
            const unsigned short* gw = W + (size_t)(bn + chunk * 16 + srow) * 512 + k0 + scol;
            __builtin_amdgcn_global_load_lds(
                (const __attribute__((address_space(1))) void*)ga,
                (__attribute__((address_space(3))) void*)(As + chunk * 16 * 32),
                16, 0, 0);
            __builtin_amdgcn_global_load_lds(
                (const __attribute__((address_space(1))) void*)gw,
                (__attribute__((address_space(3))) void*)(Bs + chunk * 16 * 32),
                16, 0, 0);
        }
        __syncthreads();

        bf16x8 af[4], bf[4];
        const int fr = lane & 15;
        const int kk = (lane >> 4) * 8;
        #pragma unroll
        for (int i = 0; i < 4; ++i) {
            af[i] = *(const bf16x8*)(As + (wm + i * 16 + fr) * 32 + kk);
            bf[i] = *(const bf16x8*)(Bs + (wn + i * 16 + fr) * 32 + kk);
        }
        #pragma unroll
        for (int i = 0; i < 4; ++i)
            #pragma unroll
            for (int j = 0; j < 4; ++j)
                acc[i][j] = __builtin_amdgcn_mfma_f32_16x16x32_bf16(
                    af[i], bf[j], acc[i][j], 0, 0, 0);
    }

    const int cn = lane & 15;
    const int cr = (lane >> 4) * 4;
    #pragma unroll
    for (int i = 0; i < 4; ++i)
        #pragma unroll
        for (int r = 0; r < 4; ++r) {
            const int m = bm + wm + i * 16 + cr + r;
            #pragma unroll
            for (int j = 0; j < 4; ++j) {
                const int n = bn + wn + j * 16 + cn;
                outB[(size_t)m * CH + n] = f2b_(acc[i][j][r] + bias[n]);
            }
        }
}

// ---------------------------------------------------------------------------
// Generic MFMA bf16 GEMM (m97 structure): out = A @ W^T, bf16 out.
// ---------------------------------------------------------------------------
__global__ __launch_bounds__(256) void gemm_bf16(
    const unsigned short* __restrict__ A, const unsigned short* __restrict__ W,
    unsigned short* __restrict__ outB, int M, int N, int Kd)
{
    __shared__ unsigned short As[128 * 32];
    __shared__ unsigned short Bs[128 * 32];
    const int tid  = threadIdx.x;
    const int wave = tid >> 6;
    const int lane = tid & 63;
    const int bm = blockIdx.y * 128;
    const int bn = blockIdx.x * 128;
    const int wm = (wave & 1) * 64;
    const int wn = (wave >> 1) * 64;
    const int srow = lane >> 2;
    const int scol = (lane & 3) * 8;

    f32x4 acc[4][4] = {};

    for (int k0 = 0; k0 < Kd; k0 += 32) {
        __syncthreads();
        #pragma unroll
        for (int c = 0; c < 2; ++c) {
            const int chunk = c * 4 + wave;
            const int row = chunk * 16 + srow;
            const unsigned short* ga = A + (size_t)(bm + row) * Kd + k0 + scol;
            const unsigned short* gw = W + (size_t)(bn + row) * Kd + k0 + scol;
            __builtin_amdgcn_global_load_lds(
                (const __attribute__((address_space(1))) void*)ga,
                (__attribute__((address_space(3))) void*)(As + chunk * 16 * 32),
                16, 0, 0);
            __builtin_amdgcn_global_load_lds(
                (const __attribute__((address_space(1))) void*)gw,
                (__attribute__((address_space(3))) void*)(Bs + chunk * 16 * 32),
                16, 0, 0);
        }
        __syncthreads();

        bf16x8 af[4], bf[4];
        const int fr = lane & 15;
        const int kk = (lane >> 4) * 8;
        #pragma unroll
        for (int i = 0; i < 4; ++i) {
            af[i] = *(const bf16x8*)(As + (wm + i * 16 + fr) * 32 + kk);
            bf[i] = *(const bf16x8*)(Bs + (wn + i * 16 + fr) * 32 + kk);
        }
        #pragma unroll
        for (int i = 0; i < 4; ++i)
            #pragma unroll
            for (int j = 0; j < 4; ++j)
                acc[i][j] = __builtin_amdgcn_mfma_f32_16x16x32_bf16(
                    af[i], bf[j], acc[i][j], 0, 0, 0);
    }

    const int cn = lane & 15;
    const int cr = (lane >> 4) * 4;
    #pragma unroll
    for (int i = 0; i < 4; ++i)
        #pragma unroll
        for (int r = 0; r < 4; ++r) {
            const int m = bm + wm + i * 16 + cr + r;
            const size_t rowoff = (size_t)m * N;
            #pragma unroll
            for (int j = 0; j < 4; ++j)
                outB[rowoff + bn + wn + j * 16 + cn] = f2b_(acc[i][j][r]);
        }
}

// ---------------------------------------------------------------------------
// Out-proj GEMM (N=256) with fused epilogue: bf16 level output + pair-mean
// downsample (in-register; each lane holds 4 consecutive rows, even base).
// ---------------------------------------------------------------------------
__global__ __launch_bounds__(256) void gemm_out_bf16(
    const unsigned short* __restrict__ A, const unsigned short* __restrict__ W,
    unsigned short* __restrict__ outB, unsigned short* __restrict__ dsB, int M)
{
    __shared__ unsigned short As[128 * 32];
    __shared__ unsigned short Bs[128 * 32];
    const int tid  = threadIdx.x;
    const int wave = tid >> 6;
    const int lane = tid & 63;
    const int bm = blockIdx.y * 128;
    const int bn = blockIdx.x * 128;
    const int wm = (wave & 1) * 64;
    const int wn = (wave >> 1) * 64;
    const int srow = lane >> 2;
    const int scol = (lane & 3) * 8;

    f32x4 acc[4][4] = {};

    for (int k0 = 0; k0 < 256; k0 += 32) {
        __syncthreads();
        #pragma unroll
        for (int c = 0; c < 2; ++c) {
            const int chunk = c * 4 + wave;
            const int row = chunk * 16 + srow;
            const unsigned short* ga = A + (size_t)(bm + row) * 256 + k0 + scol;
            const unsigned short* gw = W + (size_t)(bn + row) * 256 + k0 + scol;
            __builtin_amdgcn_global_load_lds(
                (const __attribute__((address_space(1))) void*)ga,
                (__attribute__((address_space(3))) void*)(As + chunk * 16 * 32),
                16, 0, 0);
            __builtin_amdgcn_global_load_lds(
                (const __attribute__((address_space(1))) void*)gw,
                (__attribute__((address_space(3))) void*)(Bs + chunk * 16 * 32),
                16, 0, 0);
        }
        __syncthreads();

        bf16x8 af[4], bf[4];
        const int fr = lane & 15;
        const int kk = (lane >> 4) * 8;
        #pragma unroll
        for (int i = 0; i < 4; ++i) {
            af[i] = *(const bf16x8*)(As + (wm + i * 16 + fr) * 32 + kk);
            bf[i] = *(const bf16x8*)(Bs + (wn + i * 16 + fr) * 32 + kk);
        }
        #pragma unroll
        for (int i = 0; i < 4; ++i)
            #pragma unroll
            for (int j = 0; j < 4; ++j)
                acc[i][j] = __builtin_amdgcn_mfma_f32_16x16x32_bf16(
                    af[i], bf[j], acc[i][j], 0, 0, 0);
    }

    const int cn = lane & 15;
    const int cr = (lane >> 4) * 4;   // even
    #pragma unroll
    for (int i = 0; i < 4; ++i) {
        const int base = bm + wm + i * 16 + cr;
        #pragma unroll
        for (int j = 0; j < 4; ++j) {
            const int col = bn + wn + j * 16 + cn;
            float v0 = acc[i][j][0], v1 = acc[i][j][1];
            float v2 = acc[i][j][2], v3 = acc[i][j][3];
            outB[(size_t)(base + 0) * CH + col] = f2b_(v0);
            outB[(size_t)(base + 1) * CH + col] = f2b_(v1);
            outB[(size_t)(base + 2) * CH + col] = f2b_(v2);
            outB[(size_t)(base + 3) * CH + col] = f2b_(v3);
            if (dsB) {
                dsB[(size_t)(base >> 1) * CH + col]       = f2b_(0.5f * (v0 + v1));
                dsB[(size_t)((base >> 1) + 1) * CH + col] = f2b_(0.5f * (v2 + v3));
            }
        }
    }
}

// ---------------------------------------------------------------------------
// MFMA local attention with fused width head (round-5 proven structure).
// Block = 64 positions (4 waves x 16 rows); 49,152 B LDS -> 3 blocks/CU.
// ---------------------------------------------------------------------------
__global__ __launch_bounds__(256) void attn_mfma_kernel(
    const unsigned short* __restrict__ qkv, const unsigned short* __restrict__ h16,
    const float* __restrict__ ww, const float* __restrict__ wbp,
    unsigned short* __restrict__ ov, int l)
{
    __shared__ unsigned short kv[22528];      // K [80][272] then Vt [256][88]
    __shared__ unsigned short pb[4 * 512];    // P per wave [16][32]

    const int tid  = threadIdx.x;
    const int wave = tid >> 6;
    const int lane = tid & 63;
    const int q    = lane >> 4;
    const int n    = lane & 15;

    const int blocks_per_seq = l >> 6;
    const int b  = blockIdx.x / blocks_per_seq;
    const int t0 = (blockIdx.x % blocks_per_seq) << 6;
    const size_t seqbase = (size_t)b * l;
    const int row0 = t0 + wave * 16;

    // ---- phase 1: stage K halo ----
    #pragma unroll
    for (int i = 0; i < 10; ++i) {
        int task = i * 256 + tid;
        int r = task >> 5, chunk = task & 31;
        int grow = t0 - 8 + r;
        bf16x8 val = {0, 0, 0, 0, 0, 0, 0, 0};
        if (grow >= 0 && grow < l)
            val = *(const bf16x8*)(qkv + (seqbase + grow) * 768 + 256 + chunk * 8);
        *(bf16x8*)(kv + r * 272 + chunk * 8) = val;
    }

    // ---- fused width: lane (q,n) accumulates cols [q*64, q*64+64) of row n ----
    float wdot = 0.0f;
    {
        const unsigned short* hrow = h16 + (seqbase + row0 + n) * 256 + q * 64;
        #pragma unroll
        for (int jj = 0; jj < 8; ++jj) {
            bf16x8 hv = *(const bf16x8*)(hrow + jj * 8);
            float4 wa = *((const float4*)(ww + q * 64 + jj * 8));
            float4 wc = *((const float4*)(ww + q * 64 + jj * 8 + 4));
            wdot += bf2f_(((unsigned short*)&hv)[0]) * wa.x
                  + bf2f_(((unsigned short*)&hv)[1]) * wa.y
                  + bf2f_(((unsigned short*)&hv)[2]) * wa.z
                  + bf2f_(((unsigned short*)&hv)[3]) * wa.w
                  + bf2f_(((unsigned short*)&hv)[4]) * wc.x
                  + bf2f_(((unsigned short*)&hv)[5]) * wc.y
                  + bf2f_(((unsigned short*)&hv)[6]) * wc.z
                  + bf2f_(((unsigned short*)&hv)[7]) * wc.w;
        }
    }
    wdot += __shfl_xor(wdot, 16, 64);
    wdot += __shfl_xor(wdot, 32, 64);
    const float w_n = sigmoidf_(wdot + wbp[0]) * 8.0f + 0.5f;  // width of row n

    __syncthreads();

    // Q A-fragments straight from global
    bf16x8 qf[8];
    const unsigned short* qrow = qkv + (seqbase + row0 + n) * 768;
    #pragma unroll
    for (int kk = 0; kk < 8; ++kk)
        qf[kk] = *(const bf16x8*)(qrow + kk * 32 + q * 8);

    f32x4 accS[2] = {};
    #pragma unroll
    for (int kk = 0; kk < 8; ++kk) {
        #pragma unroll
        for (int h = 0; h < 2; ++h) {
            bf16x8 bk = *(const bf16x8*)(kv + (wave * 16 + h * 16 + n) * 272 +
                                         kk * 32 + q * 8);
            accS[h] = __builtin_amdgcn_mfma_f32_16x16x32_bf16(
                qf[kk], bk, accS[h], 0, 0, 0);
        }
    }

    // widths for this lane's 4 C-layout rows (i = q*4+r), pulled via shfl
    float wd[4];
    #pragma unroll
    for (int r = 0; r < 4; ++r) wd[r] = __shfl(w_n, q * 4 + r, 64);

    // mask + scale (C-layout: col c = h*16+n, row i = q*4+r)
    float s[2][4];
    #pragma unroll
    for (int h = 0; h < 2; ++h)
        #pragma unroll
        for (int r = 0; r < 4; ++r) {
            int ii = q * 4 + r;
            int c  = h * 16 + n;
            int w  = c - ii;
            float dist = fabsf((float)w - 8.0f);
            float sm = sigmoidf_((wd[r] - dist) * 5.0f);
            float v = accS[h][r] * 0.0625f - (1.0f - sm) * 10000.0f;
            s[h][r] = (w >= 0 && w <= 16) ? v : -3.0e38f;
        }

    // softmax over the row (16 lanes of the quad hold the 32 cols)
    float mx[4], sum[4];
    #pragma unroll
    for (int r = 0; r < 4; ++r) mx[r] = fmaxf(s[0][r], s[1][r]);
    #pragma unroll
    for (int m = 1; m < 16; m <<= 1)
        #pragma unroll
        for (int r = 0; r < 4; ++r) mx[r] = fmaxf(mx[r], __shfl_xor(mx[r], m, 64));
    float e[2][4];
    #pragma unroll
    for (int h = 0; h < 2; ++h)
        #pragma unroll
        for (int r = 0; r < 4; ++r) e[h][r] = expf(s[h][r] - mx[r]);
    #pragma unroll
    for (int r = 0; r < 4; ++r) sum[r] = e[0][r] + e[1][r];
    #pragma unroll
    for (int m = 1; m < 16; m <<= 1)
        #pragma unroll
        for (int r = 0; r < 4; ++r) sum[r] += __shfl_xor(sum[r], m, 64);

    // write P (bf16), folding the o+v residual: +1 at center col c == ii+8
    #pragma unroll
    for (int h = 0; h < 2; ++h)
        #pragma unroll
        for (int r = 0; r < 4; ++r) {
            int ii = q * 4 + r, c = h * 16 + n;
            float p = e[h][r] / sum[r];
            if (c == ii + 8) p += 1.0f;
            pb[wave * 512 + ii * 32 + c] = f2b_(p);
        }
    __syncthreads();  // all waves done reading K region

    // ---- phase 2: stage V transposed into kv as Vt[256][88] ----
    #pragma unroll
    for (int p5 = 0; p5 < 5; ++p5)
        #pragma unroll
        for (int cc = 0; cc < 2; ++cc) {
            int r = p5 * 16 + (tid & 15);
            int chunk = cc * 16 + (tid >> 4);
            int grow = t0 - 8 + r;
            bf16x8 val = {0, 0, 0, 0, 0, 0, 0, 0};
            if (grow >= 0 && grow < l)
                val = *(const bf16x8*)(qkv + (seqbase + grow) * 768 + 512 + chunk * 8);
            #pragma unroll
            for (int jj = 0; jj < 8; ++jj)
                kv[(chunk * 8 + jj) * 88 + r] = ((unsigned short*)&val)[jj];
        }
    __syncthreads();

    // ---- PV: A = P (A-layout), B = Vt slices ----
    bf16x8 pf = *(const bf16x8*)(pb + wave * 512 + n * 32 + q * 8);
    const size_t obase = (seqbase + row0) * 256;
    #pragma unroll
    for (int chunk = 0; chunk < 16; ++chunk) {
        bf16x8 vf = *(const bf16x8*)(kv + (chunk * 16 + n) * 88 + wave * 16 + q * 8);
        f32x4 z = {};
        f32x4 o = __builtin_amdgcn_mfma_f32_16x16x32_bf16(pf, vf, z, 0, 0, 0);
        #pragma unroll
        for (int r = 0; r < 4; ++r)
            ov[obase + (size_t)(q * 4 + r) * 256 + chunk * 16 + n] = f2b_(o[r]);
    }
}

// ---------------------------------------------------------------------------
// Fused global-attention tail: per block (chunk of 128 t's, batch b):
//   pass 1: e[t] = exp(concat[t]·query)  (unnormalized softmax — |s| small)
//   pass 2: partials[d] = sum_t e[t]*concat[t][d]; denomP = sum_t e[t]
// grid (64, B), block 1024.
// ---------------------------------------------------------------------------
__global__ __launch_bounds__(1024) void tail_ctx_kernel(
    const unsigned short* __restrict__ l0, const unsigned short* __restrict__ l1,
    const unsigned short* __restrict__ l2, const unsigned short* __restrict__ l3,
    const float* __restrict__ query, float* __restrict__ partials,
    float* __restrict__ denomP)
{
    __shared__ float eS[128];
    const int tid = threadIdx.x;
    const int chunk = blockIdx.x, b = blockIdx.y;
    const int t0 = chunk * 128;
    const unsigned short* levp[4] = {l0, l1, l2, l3};

    // ---- pass 1: wave w computes e for t = t0 + w*8 + j ----
    const int w = tid >> 6, lane = tid & 63;
    const int lev = lane >> 4, c0 = (lane & 15) * 16;
    const unsigned short* lpbase = levp[lev] + (size_t)b * (L_SEQ >> lev) * CH;
    const float* qp = query + lev * CH + c0;
    float4 q0 = *(const float4*)(qp);
    float4 q1 = *(const float4*)(qp + 4);
    float4 q2 = *(const float4*)(qp + 8);
    float4 q3 = *(const float4*)(qp + 12);
    #pragma unroll
    for (int j = 0; j < 8; ++j) {
        int t = t0 + w * 8 + j;
        const unsigned short* p = lpbase + (size_t)(t >> lev) * CH + c0;
        float4 h0 = ldb4_(p), h1 = ldb4_(p + 4), h2 = ldb4_(p + 8), h3 = ldb4_(p + 12);
        float part = h0.x * q0.x + h0.y * q0.y + h0.z * q0.z + h0.w * q0.w
                   + h1.x * q1.x + h1.y * q1.y + h1.z * q1.z + h1.w * q1.w
                   + h2.x * q2.x + h2.y * q2.y + h2.z * q2.z + h2.w * q2.w
                   + h3.x * q3.x + h3.y * q3.y + h3.z * q3.z + h3.w * q3.w;
        #pragma unroll
        for (int m = 1; m < 64; m <<= 1) part += __shfl_xor(part, m, 64);
        if (lane == 0) eS[w * 8 + j] = expf(part);
    }
    __syncthreads();

    if (tid == 0) {
        float ds = 0.0f;
        #pragma unroll 8
        for (int i = 0; i < 128; ++i) ds += eS[i];
        denomP[b * 64 + chunk] = ds;
    }

    // ---- pass 2: weighted accumulation (rows are L2-hot from pass 1) ----
    const int dlev = tid >> 8, c = tid & 255;
    const unsigned short* lp = levp[dlev] + (size_t)b * (L_SEQ >> dlev) * CH;
    float acc = 0.0f;
    #pragma unroll 4
    for (int t = t0; t < t0 + 128; ++t)
        acc += eS[t - t0] * bf2f_(lp[(size_t)(t >> dlev) * CH + c]);
    partials[(size_t)(b * 64 + chunk) * 1024 + tid] = acc;
}

// grid (4, B), block 256: ctx[b*1024+d] = (sum over 64 chunks) / denom
__global__ __launch_bounds__(256) void ctx_reduce_kernel(
    const float* __restrict__ partials, const float* __restrict__ denomP,
    float* __restrict__ ctx)
{
    const int b = blockIdx.y;
    const int d = blockIdx.x * 256 + threadIdx.x;
    float acc = 0.0f;
    #pragma unroll
    for (int c = 0; c < 64; ++c) acc += partials[(size_t)(b * 64 + c) * 1024 + d];
    float den = 0.0f;
    #pragma unroll
    for (int c = 0; c < 64; ++c) den += denomP[b * 64 + c];
    ctx[b * 1024 + d] = acc / den;
}

// film[b,j] = ctx[b,:]·fw[j,:] + fb[j]. One wave per j, both batches.
__global__ __launch_bounds__(256) void film_kernel(
    const float* __restrict__ ctx, const float* __restrict__ fw,
    const float* __restrict__ fb, float* __restrict__ film)
{
    const int lane = threadIdx.x & 63;
    const int j = blockIdx.x * 4 + (threadIdx.x >> 6);  // 0..511
    float acc0 = 0.0f, acc1 = 0.0f;
    #pragma unroll
    for (int r = 0; r < 4; ++r) {
        float4 w4 = *((const float4*)(fw + (size_t)j * 1024 + r * 256) + lane);
        float4 c0 = *((const float4*)(ctx + r * 256) + lane);
        float4 c1 = *((const float4*)(ctx + 1024 + r * 256) + lane);
        acc0 += w4.x * c0.x + w4.y * c0.y + w4.z * c0.z + w4.w * c0.w;
        acc1 += w4.x * c1.x + w4.y * c1.y + w4.z * c1.z + w4.w * c1.w;
    }
    #pragma unroll
    for (int m = 1; m < 64; m <<= 1) {
        acc0 += __shfl_xor(acc0, m, 64);
        acc1 += __shfl_xor(acc1, m, 64);
    }
    if (lane == 0) {
        float b = fb[j];
        film[j] = acc0 + b;
        film[512 + j] = acc1 + b;
    }
}

// out = l16_0 * (1 + scale_f) + bias_f, 4 elem/thread (ushort4 -> float4)
__global__ void final_kernel(const unsigned short* __restrict__ lev0,
                             const float* __restrict__ film,
                             float* __restrict__ out)
{
    size_t n4 = ((size_t)blockIdx.x * 256 + threadIdx.x) * 4;
    int c = (int)(n4 & (CH - 1));
    int b = (int)(n4 >> 21);  // L*C = 2^21
    float4 h = ldb4_(lev0 + n4);
    const float* fs = film + b * 512;
    float4 o;
    o.x = h.x * (1.0f + fs[c + 0]) + fs[256 + c + 0];
    o.y = h.y * (1.0f + fs[c + 1]) + fs[256 + c + 1];
    o.z = h.z * (1.0f + fs[c + 2]) + fs[256 + c + 2];
    o.w = h.w * (1.0f + fs[c + 3]) + fs[256 + c + 3];
    *(float4*)(out + n4) = o;
}

extern "C" void kernel_launch(void* const* d_in, const int* in_sizes, int n_in,
                              void* d_out, int out_size, void* d_ws, size_t ws_size,
                              hipStream_t stream) {
    const float* x       = (const float*)d_in[0];
    const float* stem_w  = (const float*)d_in[1];
    const float* stem_b  = (const float*)d_in[2];
    const float* qkv_w   = (const float*)d_in[3];
    const float* width_w = (const float*)d_in[4];
    const float* width_b = (const float*)d_in[5];
    const float* out_w   = (const float*)d_in[6];
    const float* query   = (const float*)d_in[7];
    const float* film_w  = (const float*)d_in[8];
    const float* film_b  = (const float*)d_in[9];
    float* out = (float*)d_out;
    float* ws  = (float*)d_ws;

    // ---- workspace layout (fp32 region then bf16 region) ----
    float* partials = ws;                       // 131,072
    float* denomP   = partials + 131072;        // 128
    float* ctx      = denomP + 128;             // 2,048
    float* film     = ctx + 2048;               // 1,024
    unsigned short* x16g  = (unsigned short*)(film + 1024);  // 256 guard + 4,194,304
    unsigned short* h16_0 = x16g + 4194560;     // 4,194,304
    unsigned short* h16_1 = h16_0 + 4194304;    // 2,097,152
    unsigned short* h16_2 = h16_1 + 2097152;    // 1,048,576
    unsigned short* h16_3 = h16_2 + 1048576;    //   524,288
    unsigned short* qkv16 = h16_3 + 524288;     // 12,582,912
    unsigned short* ov16  = qkv16 + 12582912;   // 4,194,304
    unsigned short* l16_0 = ov16 + 4194304;     // 4,194,304
    unsigned short* l16_1 = l16_0 + 4194304;    // 2,097,152
    unsigned short* l16_2 = l16_1 + 2097152;    // 1,048,576
    unsigned short* l16_3 = l16_2 + 1048576;    //   524,288
    unsigned short* qw16  = l16_3 + 524288;     //   196,608
    unsigned short* ow16  = qw16 + 196608;      //    65,536
    unsigned short* sw16  = ow16 + 65536;       //   131,072
    unsigned short* h16[4]  = {h16_0, h16_1, h16_2, h16_3};
    unsigned short* l16[4]  = {l16_0, l16_1, l16_2, l16_3};

    // ---- fused prep (guard + x16 + all weights) ----
    prep_kernel<<<(256 + 4194304 + 196608 + 65536 + 131072) / 256, 256, 0, stream>>>(
        x, qkv_w, out_w, stem_w, x16g, qw16, ow16, sw16);

    // ---- stem conv as bf16 GEMM (A staged directly from x16) ----
    stem_gemm_bf16<<<dim3(CH / 128, B_SZ * L_SEQ / 128), 256, 0, stream>>>(
        x16g, sw16, h16_0, stem_b);

    // ---- hierarchy levels: qkv GEMM + attn + out-proj(+downsample) ----
    for (int i = 0; i < NLEV; ++i) {
        const int l = L_SEQ >> i;
        const int M = B_SZ * l;
        gemm_bf16<<<dim3(768 / 128, M / 128), 256, 0, stream>>>(
            h16[i], qw16, qkv16, M, 768, CH);
        attn_mfma_kernel<<<M / 64, 256, 0, stream>>>(
            qkv16, h16[i], width_w, width_b, ov16, l);
        gemm_out_bf16<<<dim3(CH / 128, M / 128), 256, 0, stream>>>(
            ov16, ow16, l16[i], (i < NLEV - 1) ? h16[i + 1] : nullptr, M);
    }

    // ---- fused global-attention tail + FiLM ----
    tail_ctx_kernel<<<dim3(64, B_SZ), 1024, 0, stream>>>(
        l16_0, l16_1, l16_2, l16_3, query, partials, denomP);
    ctx_reduce_kernel<<<dim3(4, B_SZ), 256, 0, stream>>>(partials, denomP, ctx);
    film_kernel<<<128, 256, 0, stream>>>(ctx, film_w, film_b, film);
    final_kernel<<<(B_SZ * L_SEQ * CH) / 1024, 256, 0, stream>>>(l16_0, film, out);
}